// Round 4
// baseline (474.564 us; speedup 1.0000x reference)
//
#include <hip/hip_runtime.h>
#include <float.h>

#define PROMPT_LEN 2048
#define VOCAB 49408
#define DIM 768
#define ROWS_TOTAL (VOCAB + PROMPT_LEN)   // 51456
#define NS 16          // candidate stripes
#define TM 128         // prompts per score block
#define TN 32          // candidates per tile
#define KC 64          // k-chunk
#define KQ (KC/4)
#define NCHUNK (DIM/KC)
#define EPS 0.008f     // fp32 ambiguity margin (~8x error bound ~1e-3)

// ws layout (bytes):
//   csq   : [0, VOCAB*4)
//   cand  : [VOCAB*4, VOCAB*8)
//   psq   : [VOCAB*8, +PROMPT_LEN*4)
//   scal  : +16   ([0]=count, [1]=cmin bits, [2]=pmax bits, [3]=nAmb)
//   AB1   : +PROMPT_LEN*NS*4
//   AB2   : +PROMPT_LEN*NS*4
//   AIdx  : +PROMPT_LEN*NS*4
//   amb   : +PROMPT_LEN*4

__global__ void k_init(unsigned* scal) {
    if (threadIdx.x == 0) {
        scal[0] = 0u;
        scal[1] = 0x7F800000u;   // +inf
        scal[2] = 0u;
        scal[3] = 0u;            // ambiguous count
    }
}

__global__ void __launch_bounds__(256) k_sumsq(const float* __restrict__ prompt,
                                               const float* __restrict__ clip,
                                               float* __restrict__ csq,
                                               float* __restrict__ psq) {
    int wid  = threadIdx.x >> 6;
    int lane = threadIdx.x & 63;
    int base = blockIdx.x * 32 + wid * 8;      // 1608*32 == 51456

    for (int r = base; r < base + 8; r += 2) {
        const float* s0 = (r     < VOCAB) ? clip + (size_t)r * DIM
                                          : prompt + (size_t)(r - VOCAB) * DIM;
        const float* s1 = (r + 1 < VOCAB) ? clip + (size_t)(r + 1) * DIM
                                          : prompt + (size_t)(r + 1 - VOCAB) * DIM;
        float4 a0 = ((const float4*)s0)[lane];
        float4 a1 = ((const float4*)s0)[64 + lane];
        float4 a2 = ((const float4*)s0)[128 + lane];
        float4 b0 = ((const float4*)s1)[lane];
        float4 b1 = ((const float4*)s1)[64 + lane];
        float4 b2 = ((const float4*)s1)[128 + lane];
        float sA = a0.x*a0.x + a0.y*a0.y + a0.z*a0.z + a0.w*a0.w
                 + a1.x*a1.x + a1.y*a1.y + a1.z*a1.z + a1.w*a1.w
                 + a2.x*a2.x + a2.y*a2.y + a2.z*a2.z + a2.w*a2.w;
        float sB = b0.x*b0.x + b0.y*b0.y + b0.z*b0.z + b0.w*b0.w
                 + b1.x*b1.x + b1.y*b1.y + b1.z*b1.z + b1.w*b1.w
                 + b2.x*b2.x + b2.y*b2.y + b2.z*b2.z + b2.w*b2.w;
        #pragma unroll
        for (int m = 32; m >= 1; m >>= 1) {
            sA += __shfl_xor(sA, m, 64);
            sB += __shfl_xor(sB, m, 64);
        }
        if (lane == 0) {
            if (r < VOCAB) csq[r] = sA; else psq[r - VOCAB] = sA;
            if (r + 1 < VOCAB) csq[r + 1] = sB; else psq[r + 1 - VOCAB] = sB;
        }
    }
}

__global__ void __launch_bounds__(256) k_reduce(const float* __restrict__ csq,
                                                const float* __restrict__ psq,
                                                unsigned* __restrict__ scal) {
    int tid = blockIdx.x * 256 + threadIdx.x;
    const int stride = 64 * 256;
    float mn = 1e30f, mx = 0.f;
    for (int i = tid; i < VOCAB; i += stride)      mn = fminf(mn, csq[i]);
    for (int i = tid; i < PROMPT_LEN; i += stride) mx = fmaxf(mx, psq[i]);
    #pragma unroll
    for (int m = 32; m >= 1; m >>= 1) {
        mn = fminf(mn, __shfl_xor(mn, m, 64));
        mx = fmaxf(mx, __shfl_xor(mx, m, 64));
    }
    __shared__ float smn[4], smx[4];
    int wid = threadIdx.x >> 6, lane = threadIdx.x & 63;
    if (lane == 0) { smn[wid] = mn; smx[wid] = mx; }
    __syncthreads();
    if (threadIdx.x == 0) {
        mn = fminf(fminf(smn[0], smn[1]), fminf(smn[2], smn[3]));
        mx = fmaxf(fmaxf(smx[0], smx[1]), fmaxf(smx[2], smx[3]));
        atomicMin(&scal[1], __float_as_uint(mn));
        atomicMax(&scal[2], __float_as_uint(mx));
    }
}

// Exact pruning: keep v iff csq[v] - 2B*sqrt(csq[v]) <= min_u (csq[u] + 2B*sqrt(csq[u]))
__global__ void k_compact(const float* __restrict__ csq, int* __restrict__ cand,
                          unsigned* __restrict__ scal) {
    float cmin    = __uint_as_float(scal[1]);
    float pmax_sq = __uint_as_float(scal[2]);
    float B  = sqrtf(pmax_sq) * 1.0001f + 1e-6f;
    float U  = cmin + 2.f * B * sqrtf(cmin) + 1.0f;
    float sT = B + sqrtf(B * B + U);
    float T  = sT * sT;
    int v = blockIdx.x * blockDim.x + threadIdx.x;
    if (v < VOCAB && csq[v] <= T) {
        int pos = atomicAdd((int*)&scal[0], 1);
        cand[pos] = v;
    }
}

// Register-tiled fp32 GEMM scoring: block = (m-tile mi, stripe s).
// Per-block L2 traffic = (TM+TN)*3KB per tile instead of TM*TN*3KB.
__global__ void __launch_bounds__(256) k_score(const float* __restrict__ prompt,
                                               const float* __restrict__ clip,
                                               const float* __restrict__ csq,
                                               const int* __restrict__ cand,
                                               const unsigned* __restrict__ scal,
                                               float* __restrict__ AB1,
                                               float* __restrict__ AB2,
                                               int* __restrict__ AIdx) {
    int mi = blockIdx.x;            // 0..15
    int s  = blockIdx.y;            // 0..NS-1
    int m0 = mi * TM;
    int count  = (int)scal[0];
    int ntiles = (count + TN - 1) / TN;

    int tid = threadIdx.x;
    int mt = tid & 31;              // 32 m-threads (rows mt, mt+32, mt+64, mt+96)
    int nt = tid >> 5;              // 8 n-threads  (cols nt*4 .. nt*4+3)

    __shared__ float Pl[TM][KC + 4];
    __shared__ float Cl[TN][KC + 4];
    __shared__ int   candS[TN];
    __shared__ float csqS[TN];
    __shared__ float mB1[TM][8], mB2[TM][8];
    __shared__ int   mBI[TM][8];

    float b1[4], b2[4]; int bi[4];
    #pragma unroll
    for (int j = 0; j < 4; ++j) { b1[j] = FLT_MAX; b2[j] = FLT_MAX; bi[j] = 0x7fffffff; }

    for (int tile = s; tile < ntiles; tile += NS) {
        __syncthreads();           // prior tile's candS/csqS reads complete
        if (tid < TN) {
            int ci = tile * TN + tid;
            int v  = (ci < count) ? cand[ci] : 0;
            candS[tid] = v;
            csqS[tid]  = (ci < count) ? csq[v] : FLT_MAX;
        }
        __syncthreads();

        float acc[4][4];
        #pragma unroll
        for (int j = 0; j < 4; ++j)
            #pragma unroll
            for (int l = 0; l < 4; ++l) acc[j][l] = 0.f;

        for (int kc = 0; kc < DIM; kc += KC) {
            __syncthreads();       // prior chunk's LDS reads complete
            #pragma unroll
            for (int f = 0; f < 8; ++f) {        // stage P: 2048 float4
                int j = tid + 256 * f;
                int r = j >> 4, c4 = j & 15;
                float4 v4 = *(const float4*)(prompt + (size_t)(m0 + r) * DIM + kc + c4 * 4);
                *(float4*)&Pl[r][c4 * 4] = v4;
            }
            #pragma unroll
            for (int f = 0; f < 2; ++f) {        // stage C: 512 float4
                int j = tid + 256 * f;
                int n = j >> 4, c4 = j & 15;
                float4 v4 = *(const float4*)(clip + (size_t)candS[n] * DIM + kc + c4 * 4);
                *(float4*)&Cl[n][c4 * 4] = v4;
            }
            __syncthreads();
            #pragma unroll
            for (int q = 0; q < KQ; ++q) {
                float4 p[4], c[4];
                #pragma unroll
                for (int j = 0; j < 4; ++j) p[j] = *(const float4*)&Pl[mt + 32 * j][q * 4];
                #pragma unroll
                for (int l = 0; l < 4; ++l) c[l] = *(const float4*)&Cl[nt * 4 + l][q * 4];
                #pragma unroll
                for (int j = 0; j < 4; ++j)
                    #pragma unroll
                    for (int l = 0; l < 4; ++l) {
                        acc[j][l] = fmaf(p[j].x, c[l].x, acc[j][l]);
                        acc[j][l] = fmaf(p[j].y, c[l].y, acc[j][l]);
                        acc[j][l] = fmaf(p[j].z, c[l].z, acc[j][l]);
                        acc[j][l] = fmaf(p[j].w, c[l].w, acc[j][l]);
                    }
            }
        }

        #pragma unroll
        for (int l = 0; l < 4; ++l) {
            float cs = csqS[nt * 4 + l];
            if (cs < FLT_MAX) {
                int v = candS[nt * 4 + l];
                #pragma unroll
                for (int j = 0; j < 4; ++j) {
                    float d2 = fmaf(-2.f, acc[j][l], cs);
                    if (d2 < b1[j]) { b2[j] = b1[j]; b1[j] = d2; bi[j] = v; }
                    else if (d2 <= b2[j]) b2[j] = d2;   // d2==b1 -> gap 0 -> fallback
                }
            }
        }
    }

    __syncthreads();
    #pragma unroll
    for (int j = 0; j < 4; ++j) {
        mB1[mt + 32 * j][nt] = b1[j];
        mB2[mt + 32 * j][nt] = b2[j];
        mBI[mt + 32 * j][nt] = bi[j];
    }
    __syncthreads();
    if (tid < TM) {
        float B1 = FLT_MAX, B2 = FLT_MAX; int BI = 0x7fffffff;
        #pragma unroll
        for (int w = 0; w < 8; ++w) {
            float y1 = mB1[tid][w], y2 = mB2[tid][w]; int yi = mBI[tid][w];
            if (y1 < B1) { B2 = fminf(B1, y2); B1 = y1; BI = yi; }
            else         { B2 = fminf(B2, fminf(y1, y2)); }
        }
        int m = m0 + tid;
        AB1[m * NS + s] = B1;
        AB2[m * NS + s] = B2;
        AIdx[m * NS + s] = BI;
    }
}

// Wave per prompt: merge NS stripe-triples; clear prompts write output,
// ambiguous ones (gap < EPS) go to the fallback list.
__global__ void __launch_bounds__(256) k_merge(const float* __restrict__ prompt,
                                               const float* __restrict__ clip,
                                               const float* __restrict__ AB1,
                                               const float* __restrict__ AB2,
                                               const int* __restrict__ AIdx,
                                               unsigned* __restrict__ scal,
                                               int* __restrict__ amb,
                                               float* __restrict__ out) {
    int wid  = threadIdx.x >> 6;
    int lane = threadIdx.x & 63;
    int m = blockIdx.x * 4 + wid;
    int s = lane & 15;

    float b1 = AB1[m * NS + s];
    float b2 = AB2[m * NS + s];
    int   bi = AIdx[m * NS + s];
    #pragma unroll
    for (int msk = 1; msk <= 8; msk <<= 1) {
        float y1 = __shfl_xor(b1, msk, 64);
        float y2 = __shfl_xor(b2, msk, 64);
        int   yi = __shfl_xor(bi, msk, 64);
        if (y1 < b1) { b2 = fminf(b1, y2); b1 = y1; bi = yi; }
        else         { b2 = fminf(b2, fminf(y1, y2)); }
    }

    if (b2 - b1 < EPS) {
        if (lane == 0) {
            int pos = atomicAdd((int*)&scal[3], 1);
            amb[pos] = m;
        }
    } else {
        const float* crow = clip + (size_t)bi * DIM;
        const float* prow = prompt + (size_t)m * DIM;
        #pragma unroll
        for (int i = 0; i < 3; ++i) {
            float4 c = ((const float4*)crow)[i * 64 + lane];
            float4 p = ((const float4*)prow)[i * 64 + lane];
            float4 o;
            o.x = (c.x - p.x) + p.x;
            o.y = (c.y - p.y) + p.y;
            o.z = (c.z - p.z) + p.z;
            o.w = (c.w - p.w) + p.w;
            ((float4*)(out + (size_t)m * DIM))[i * 64 + lane] = o;
        }
        if (lane == 0) out[(size_t)PROMPT_LEN * DIM + m] = (float)bi;
    }
}

// Exact fp64 rescan for ambiguous prompts (block per prompt, grid-stride).
__global__ void __launch_bounds__(256) k_fallback(const float* __restrict__ prompt,
                                                  const float* __restrict__ clip,
                                                  const int* __restrict__ cand,
                                                  const unsigned* __restrict__ scal,
                                                  const int* __restrict__ amb,
                                                  float* __restrict__ out) {
    int nAmb  = (int)scal[3];
    int count = (int)scal[0];
    int wid  = threadIdx.x >> 6;
    int lane = threadIdx.x & 63;

    __shared__ double fB[4];
    __shared__ int    fI[4];
    __shared__ int    sWin;

    for (int a = blockIdx.x; a < nAmb; a += gridDim.x) {
        int m = amb[a];
        const float* prow = prompt + (size_t)m * DIM;
        double pd[12];
        #pragma unroll
        for (int i = 0; i < 3; ++i) {
            float4 v = ((const float4*)prow)[i * 64 + lane];
            pd[i*4+0] = (double)v.x; pd[i*4+1] = (double)v.y;
            pd[i*4+2] = (double)v.z; pd[i*4+3] = (double)v.w;
        }
        double best = 1e300;
        int bestIdx = 0x7fffffff;
        for (int ci = wid; ci < count; ci += 4) {
            int v = cand[ci];
            const float* crow = clip + (size_t)v * DIM;
            double sd = 0.0;
            #pragma unroll
            for (int i = 0; i < 3; ++i) {
                float4 c = ((const float4*)crow)[i * 64 + lane];
                double d0 = (double)c.x - pd[i*4+0];
                double d1 = (double)c.y - pd[i*4+1];
                double d2 = (double)c.z - pd[i*4+2];
                double d3 = (double)c.w - pd[i*4+3];
                sd = fma(d0, d0, sd); sd = fma(d1, d1, sd);
                sd = fma(d2, d2, sd); sd = fma(d3, d3, sd);
            }
            #pragma unroll
            for (int msk = 32; msk >= 1; msk >>= 1) sd += __shfl_xor(sd, msk, 64);
            if (sd < best || (sd == best && v < bestIdx)) { best = sd; bestIdx = v; }
        }
        if (lane == 0) { fB[wid] = best; fI[wid] = bestIdx; }
        __syncthreads();
        if (threadIdx.x == 0) {
            double b = fB[0]; int bi2 = fI[0];
            #pragma unroll
            for (int w = 1; w < 4; ++w)
                if (fB[w] < b || (fB[w] == b && fI[w] < bi2)) { b = fB[w]; bi2 = fI[w]; }
            sWin = bi2;
        }
        __syncthreads();
        int win = sWin;

        if (threadIdx.x < 192) {
            float4 c = ((const float4*)(clip + (size_t)win * DIM))[threadIdx.x];
            float4 p = ((const float4*)prow)[threadIdx.x];
            float4 o;
            o.x = (c.x - p.x) + p.x;
            o.y = (c.y - p.y) + p.y;
            o.z = (c.z - p.z) + p.z;
            o.w = (c.w - p.w) + p.w;
            ((float4*)(out + (size_t)m * DIM))[threadIdx.x] = o;
        }
        if (threadIdx.x == 0) out[(size_t)PROMPT_LEN * DIM + m] = (float)win;
        __syncthreads();
    }
}

extern "C" void kernel_launch(void* const* d_in, const int* in_sizes, int n_in,
                              void* d_out, int out_size, void* d_ws, size_t ws_size,
                              hipStream_t stream) {
    const float* prompt = (const float*)d_in[0];
    const float* clip   = (const float*)d_in[1];
    float* out = (float*)d_out;

    char* w = (char*)d_ws;
    float*    csq  = (float*)w;                                  w += (size_t)VOCAB * 4;
    int*      cand = (int*)w;                                    w += (size_t)VOCAB * 4;
    float*    psq  = (float*)w;                                  w += (size_t)PROMPT_LEN * 4;
    unsigned* scal = (unsigned*)w;                               w += 16;
    float*    AB1  = (float*)w;                                  w += (size_t)PROMPT_LEN * NS * 4;
    float*    AB2  = (float*)w;                                  w += (size_t)PROMPT_LEN * NS * 4;
    int*      AIdx = (int*)w;                                    w += (size_t)PROMPT_LEN * NS * 4;
    int*      amb  = (int*)w;

    k_init<<<1, 64, 0, stream>>>(scal);
    k_sumsq<<<ROWS_TOTAL / 32, 256, 0, stream>>>(prompt, clip, csq, psq);
    k_reduce<<<64, 256, 0, stream>>>(csq, psq, scal);
    k_compact<<<(VOCAB + 255) / 256, 256, 0, stream>>>(csq, cand, scal);
    k_score<<<dim3(PROMPT_LEN / TM, NS), 256, 0, stream>>>(prompt, clip, csq, cand, scal,
                                                           AB1, AB2, AIdx);
    k_merge<<<PROMPT_LEN / 4, 256, 0, stream>>>(prompt, clip, AB1, AB2, AIdx, scal, amb, out);
    k_fallback<<<256, 256, 0, stream>>>(prompt, clip, cand, scal, amb, out);
}

// Round 6
// 359.696 us; speedup vs baseline: 1.3193x; 1.3193x over previous
//
#include <hip/hip_runtime.h>
#include <float.h>

#define PROMPT_LEN 2048
#define VOCAB 49408
#define DIM 768
#define ROWS_TOTAL (VOCAB + PROMPT_LEN)   // 51456
#define NS 16          // candidate stripes
#define TM 64          // prompts per score block
#define TN 32          // candidates per tile
#define KC 64          // k-chunk
#define KQ (KC / 4)
#define EPS 0.008f     // fp32 ambiguity margin (validated R3/R4)

// ws: csq[VOCAB] | cand[VOCAB] | scal[8] | AB1 | AB2 | AIdx | amb
// scal: [0]=cand count, [1]=cmin bits, [2]=pmax bits, [3]=amb count
// No init kernel: ws poison is 0xAAAAAAAA. atomicMin on UNSIGNED bits: poison
// (2.86e9) loses to any positive-float pattern. atomicMax on INT bits: poison
// is negative, loses to any positive-float pattern. scal[0] zeroed by sumsq
// block 0 (read only by the NEXT kernel); scal[3] zeroed by compact thread 0.

// 1024 threads = 16 waves; 8 rows/wave, 2-row unroll. 402 blocks.
__global__ void __launch_bounds__(1024) k_sumsq(const float* __restrict__ prompt,
                                                const float* __restrict__ clip,
                                                float* __restrict__ csq,
                                                unsigned* __restrict__ scal) {
    int tid  = threadIdx.x;
    int wid  = tid >> 6;
    int lane = tid & 63;
    int base = blockIdx.x * 128 + wid * 8;     // 402*128 == 51456

    if (blockIdx.x == 0 && tid == 0) scal[0] = 0u;   // cand count for k_compact

    float locMin = FLT_MAX, locMax = 0.f;
    for (int r = base; r < base + 8; r += 2) {
        const float* s0 = (r     < VOCAB) ? clip + (size_t)r * DIM
                                          : prompt + (size_t)(r - VOCAB) * DIM;
        const float* s1 = (r + 1 < VOCAB) ? clip + (size_t)(r + 1) * DIM
                                          : prompt + (size_t)(r + 1 - VOCAB) * DIM;
        float4 a0 = ((const float4*)s0)[lane];
        float4 a1 = ((const float4*)s0)[64 + lane];
        float4 a2 = ((const float4*)s0)[128 + lane];
        float4 b0 = ((const float4*)s1)[lane];
        float4 b1 = ((const float4*)s1)[64 + lane];
        float4 b2 = ((const float4*)s1)[128 + lane];
        float sA = a0.x*a0.x + a0.y*a0.y + a0.z*a0.z + a0.w*a0.w
                 + a1.x*a1.x + a1.y*a1.y + a1.z*a1.z + a1.w*a1.w
                 + a2.x*a2.x + a2.y*a2.y + a2.z*a2.z + a2.w*a2.w;
        float sB = b0.x*b0.x + b0.y*b0.y + b0.z*b0.z + b0.w*b0.w
                 + b1.x*b1.x + b1.y*b1.y + b1.z*b1.z + b1.w*b1.w
                 + b2.x*b2.x + b2.y*b2.y + b2.z*b2.z + b2.w*b2.w;
        #pragma unroll
        for (int m = 32; m >= 1; m >>= 1) {
            sA += __shfl_xor(sA, m, 64);
            sB += __shfl_xor(sB, m, 64);
        }
        if (r < VOCAB)     locMin = fminf(locMin, sA); else locMax = fmaxf(locMax, sA);
        if (r + 1 < VOCAB) locMin = fminf(locMin, sB); else locMax = fmaxf(locMax, sB);
        if (lane == 0) {
            if (r < VOCAB)     csq[r] = sA;
            if (r + 1 < VOCAB) csq[r + 1] = sB;
        }
    }
    __shared__ float smn[16], smx[16];
    if (lane == 0) { smn[wid] = locMin; smx[wid] = locMax; }
    __syncthreads();
    if (tid == 0) {
        float mn = FLT_MAX, mx = 0.f;
        #pragma unroll
        for (int w = 0; w < 16; ++w) { mn = fminf(mn, smn[w]); mx = fmaxf(mx, smx[w]); }
        atomicMin(&scal[1], __float_as_uint(mn));          // unsigned: poison-safe
        atomicMax((int*)&scal[2], (int)__float_as_uint(mx)); // int: poison-safe
    }
}

// Exact pruning: keep v iff csq[v] - 2B*sqrt(csq[v]) <= min_u (csq[u] + 2B*sqrt(csq[u]))
__global__ void __launch_bounds__(256) k_compact(const float* __restrict__ csq,
                                                 int* __restrict__ cand,
                                                 unsigned* __restrict__ scal) {
    float cmin    = __uint_as_float(scal[1]);
    float pmax_sq = __uint_as_float(scal[2]);
    float B  = sqrtf(pmax_sq) * 1.0001f + 1e-6f;
    float U  = cmin + 2.f * B * sqrtf(cmin) + 1.0f;
    float sT = B + sqrtf(B * B + U);
    float T  = sT * sT;
    int v = blockIdx.x * 256 + threadIdx.x;
    if (v == 0) scal[3] = 0u;                  // amb count for k_merge (next kernel)
    __shared__ int cnt, basep;
    if (threadIdx.x == 0) cnt = 0;
    __syncthreads();
    int keep = (v < VOCAB) && (csq[v] <= T);
    int pos = 0;
    if (keep) pos = atomicAdd(&cnt, 1);
    __syncthreads();
    if (threadIdx.x == 0 && cnt > 0) basep = atomicAdd((int*)&scal[0], cnt);
    __syncthreads();
    if (keep) cand[basep + pos] = v;
}

// Register-tiled fp32 scorer. Block = (m-tile mi of 64 prompts, stripe s).
// Grid 512 blocks, ~32.5 KB LDS -> 4 blocks/CU.
__global__ void __launch_bounds__(256, 4) k_score(const float* __restrict__ prompt,
                                                  const float* __restrict__ clip,
                                                  const float* __restrict__ csq,
                                                  const int* __restrict__ cand,
                                                  const unsigned* __restrict__ scal,
                                                  float* __restrict__ AB1,
                                                  float* __restrict__ AB2,
                                                  int* __restrict__ AIdx) {
    int mi = blockIdx.x / NS;       // 0..31
    int s  = blockIdx.x % NS;       // 0..15
    int m0 = mi * TM;
    int count  = (int)scal[0];
    int ntiles = (count + TN - 1) / TN;

    int tid = threadIdx.x;
    int mt = tid & 31;              // rows mt, mt+32
    int nt = tid >> 5;              // cols nt*4 .. nt*4+3

    __shared__ float Pl[TM][KC + 4];
    __shared__ float Cl[TN][KC + 4];
    __shared__ int   candS[TN];
    __shared__ float csqS[TN];
    __shared__ float mB1[TM][8], mB2[TM][8];
    __shared__ int   mBI[TM][8];

    float b1[2], b2[2]; int bi[2];
    #pragma unroll
    for (int j = 0; j < 2; ++j) { b1[j] = FLT_MAX; b2[j] = FLT_MAX; bi[j] = 0x7fffffff; }

    for (int tile = s; tile < ntiles; tile += NS) {
        __syncthreads();
        if (tid < TN) {
            int ci = tile * TN + tid;
            int v  = (ci < count) ? cand[ci] : 0;
            candS[tid] = v;
            csqS[tid]  = (ci < count) ? csq[v] : FLT_MAX;
        }
        __syncthreads();

        float acc[2][4];
        #pragma unroll
        for (int j = 0; j < 2; ++j)
            #pragma unroll
            for (int l = 0; l < 4; ++l) acc[j][l] = 0.f;

        for (int kc = 0; kc < DIM; kc += KC) {
            __syncthreads();
            #pragma unroll
            for (int f = 0; f < 4; ++f) {          // stage P: 1024 float4
                int j = tid + 256 * f;
                int r = j >> 4, c4 = j & 15;
                float4 v4 = *(const float4*)(prompt + (size_t)(m0 + r) * DIM + kc + c4 * 4);
                *(float4*)&Pl[r][c4 * 4] = v4;
            }
            #pragma unroll
            for (int f = 0; f < 2; ++f) {          // stage C: 512 float4
                int j = tid + 256 * f;
                int n = j >> 4, c4 = j & 15;
                float4 v4 = *(const float4*)(clip + (size_t)candS[n] * DIM + kc + c4 * 4);
                *(float4*)&Cl[n][c4 * 4] = v4;
            }
            __syncthreads();
            #pragma unroll
            for (int q = 0; q < KQ; ++q) {
                float4 p[2], c[4];
                p[0] = *(const float4*)&Pl[mt][q * 4];
                p[1] = *(const float4*)&Pl[mt + 32][q * 4];
                #pragma unroll
                for (int l = 0; l < 4; ++l) c[l] = *(const float4*)&Cl[nt * 4 + l][q * 4];
                #pragma unroll
                for (int j = 0; j < 2; ++j)
                    #pragma unroll
                    for (int l = 0; l < 4; ++l) {
                        acc[j][l] = fmaf(p[j].x, c[l].x, acc[j][l]);
                        acc[j][l] = fmaf(p[j].y, c[l].y, acc[j][l]);
                        acc[j][l] = fmaf(p[j].z, c[l].z, acc[j][l]);
                        acc[j][l] = fmaf(p[j].w, c[l].w, acc[j][l]);
                    }
            }
        }

        #pragma unroll
        for (int l = 0; l < 4; ++l) {
            float cs = csqS[nt * 4 + l];
            if (cs < FLT_MAX) {
                int v = candS[nt * 4 + l];
                #pragma unroll
                for (int j = 0; j < 2; ++j) {
                    float d2 = fmaf(-2.f, acc[j][l], cs);
                    if (d2 < b1[j]) { b2[j] = b1[j]; b1[j] = d2; bi[j] = v; }
                    else if (d2 <= b2[j]) b2[j] = d2;   // equality -> gap 0 -> fallback
                }
            }
        }
    }

    __syncthreads();
    #pragma unroll
    for (int j = 0; j < 2; ++j) {
        mB1[mt + 32 * j][nt] = b1[j];
        mB2[mt + 32 * j][nt] = b2[j];
        mBI[mt + 32 * j][nt] = bi[j];
    }
    __syncthreads();
    if (tid < TM) {
        float B1 = FLT_MAX, B2 = FLT_MAX; int BI = 0x7fffffff;
        #pragma unroll
        for (int w = 0; w < 8; ++w) {
            float y1 = mB1[tid][w], y2 = mB2[tid][w]; int yi = mBI[tid][w];
            if (y1 < B1) { B2 = fminf(B1, y2); B1 = y1; BI = yi; }
            else         { B2 = fminf(B2, fminf(y1, y2)); }
        }
        int m = m0 + tid;
        AB1[m * NS + s] = B1;
        AB2[m * NS + s] = B2;
        AIdx[m * NS + s] = BI;
    }
}

// Wave per prompt: merge NS stripe-triples; clear prompts write output,
// ambiguous ones (gap < EPS) go to the fallback list. (R4-proven.)
__global__ void __launch_bounds__(256) k_merge(const float* __restrict__ prompt,
                                               const float* __restrict__ clip,
                                               const float* __restrict__ AB1,
                                               const float* __restrict__ AB2,
                                               const int* __restrict__ AIdx,
                                               unsigned* __restrict__ scal,
                                               int* __restrict__ amb,
                                               float* __restrict__ out) {
    int wid  = threadIdx.x >> 6;
    int lane = threadIdx.x & 63;
    int m = blockIdx.x * 4 + wid;
    int s = lane & 15;

    float b1 = AB1[m * NS + s];
    float b2 = AB2[m * NS + s];
    int   bi = AIdx[m * NS + s];
    #pragma unroll
    for (int msk = 1; msk <= 8; msk <<= 1) {
        float y1 = __shfl_xor(b1, msk, 64);
        float y2 = __shfl_xor(b2, msk, 64);
        int   yi = __shfl_xor(bi, msk, 64);
        if (y1 < b1) { b2 = fminf(b1, y2); b1 = y1; bi = yi; }
        else         { b2 = fminf(b2, fminf(y1, y2)); }
    }

    if (b2 - b1 < EPS) {
        if (lane == 0) {
            int pos = atomicAdd((int*)&scal[3], 1);
            amb[pos] = m;
        }
    } else {
        const float* crow = clip + (size_t)bi * DIM;
        const float* prow = prompt + (size_t)m * DIM;
        #pragma unroll
        for (int i = 0; i < 3; ++i) {
            float4 c = ((const float4*)crow)[i * 64 + lane];
            float4 p = ((const float4*)prow)[i * 64 + lane];
            float4 o;
            o.x = (c.x - p.x) + p.x;
            o.y = (c.y - p.y) + p.y;
            o.z = (c.z - p.z) + p.z;
            o.w = (c.w - p.w) + p.w;
            ((float4*)(out + (size_t)m * DIM))[i * 64 + lane] = o;
        }
        if (lane == 0) out[(size_t)PROMPT_LEN * DIM + m] = (float)bi;
    }
}

// Exact fp64 rescan, 1024 threads (16 waves) per ambiguous prompt.
__global__ void __launch_bounds__(1024) k_fallback(const float* __restrict__ prompt,
                                                   const float* __restrict__ clip,
                                                   const int* __restrict__ cand,
                                                   const unsigned* __restrict__ scal,
                                                   const int* __restrict__ amb,
                                                   float* __restrict__ out) {
    int nAmb  = (int)scal[3];
    int count = (int)scal[0];
    int tid  = threadIdx.x;
    int wid  = tid >> 6;
    int lane = tid & 63;

    __shared__ double fB[16];
    __shared__ int    fI[16];
    __shared__ int    sWin;

    for (int a = blockIdx.x; a < nAmb; a += gridDim.x) {
        int m = amb[a];
        const float* prow = prompt + (size_t)m * DIM;
        double pd[12];
        #pragma unroll
        for (int i = 0; i < 3; ++i) {
            float4 v = ((const float4*)prow)[i * 64 + lane];
            pd[i*4+0] = (double)v.x; pd[i*4+1] = (double)v.y;
            pd[i*4+2] = (double)v.z; pd[i*4+3] = (double)v.w;
        }
        double best = 1e300;
        int bestIdx = 0x7fffffff;
        for (int ci = wid; ci < count; ci += 16) {
            int v = cand[ci];
            const float* crow = clip + (size_t)v * DIM;
            double sd = 0.0;
            #pragma unroll
            for (int i = 0; i < 3; ++i) {
                float4 c = ((const float4*)crow)[i * 64 + lane];
                double d0 = (double)c.x - pd[i*4+0];
                double d1 = (double)c.y - pd[i*4+1];
                double d2 = (double)c.z - pd[i*4+2];
                double d3 = (double)c.w - pd[i*4+3];
                sd = fma(d0, d0, sd); sd = fma(d1, d1, sd);
                sd = fma(d2, d2, sd); sd = fma(d3, d3, sd);
            }
            #pragma unroll
            for (int msk = 32; msk >= 1; msk >>= 1) sd += __shfl_xor(sd, msk, 64);
            if (sd < best || (sd == best && v < bestIdx)) { best = sd; bestIdx = v; }
        }
        if (lane == 0) { fB[wid] = best; fI[wid] = bestIdx; }
        __syncthreads();
        if (tid == 0) {
            double b = fB[0]; int bi2 = fI[0];
            #pragma unroll
            for (int w = 1; w < 16; ++w)
                if (fB[w] < b || (fB[w] == b && fI[w] < bi2)) { b = fB[w]; bi2 = fI[w]; }
            sWin = bi2;
        }
        __syncthreads();
        int win = sWin;

        if (tid < 192) {
            float4 c = ((const float4*)(clip + (size_t)win * DIM))[tid];
            float4 p = ((const float4*)prow)[tid];
            float4 o;
            o.x = (c.x - p.x) + p.x;
            o.y = (c.y - p.y) + p.y;
            o.z = (c.z - p.z) + p.z;
            o.w = (c.w - p.w) + p.w;
            ((float4*)(out + (size_t)m * DIM))[tid] = o;
        }
        if (tid == 0) out[(size_t)PROMPT_LEN * DIM + m] = (float)win;
        __syncthreads();
    }
}

extern "C" void kernel_launch(void* const* d_in, const int* in_sizes, int n_in,
                              void* d_out, int out_size, void* d_ws, size_t ws_size,
                              hipStream_t stream) {
    const float* prompt = (const float*)d_in[0];
    const float* clip   = (const float*)d_in[1];
    float* out = (float*)d_out;

    char* w = (char*)d_ws;
    float*    csq  = (float*)w;                    w += (size_t)VOCAB * 4;
    int*      cand = (int*)w;                      w += (size_t)VOCAB * 4;
    unsigned* scal = (unsigned*)w;                 w += 32;
    float*    AB1  = (float*)w;                    w += (size_t)PROMPT_LEN * NS * 4;
    float*    AB2  = (float*)w;                    w += (size_t)PROMPT_LEN * NS * 4;
    int*      AIdx = (int*)w;                      w += (size_t)PROMPT_LEN * NS * 4;
    int*      amb  = (int*)w;

    k_sumsq<<<ROWS_TOTAL / 128, 1024, 0, stream>>>(prompt, clip, csq, scal);
    k_compact<<<(VOCAB + 255) / 256, 256, 0, stream>>>(csq, cand, scal);
    k_score<<<(PROMPT_LEN / TM) * NS, 256, 0, stream>>>(prompt, clip, csq, cand, scal,
                                                        AB1, AB2, AIdx);
    k_merge<<<PROMPT_LEN / 4, 256, 0, stream>>>(prompt, clip, AB1, AB2, AIdx, scal, amb, out);
    k_fallback<<<128, 1024, 0, stream>>>(prompt, clip, cand, scal, amb, out);
}